// Round 11
// baseline (299.908 us; speedup 1.0000x reference)
//
#include <hip/hip_runtime.h>
#include <hip/hip_fp16.h>

#define N_NODES 100000
#define N_EDGES 1600000
#define ELL_W 64
#define NCHUNK 64                  // edge chunks
#define NSEG 4                     // node segments
#define CH (N_EDGES / NCHUNK)      // 25000 edges per chunk
#define SEGN (N_NODES / NSEG)      // 25000 nodes per segment

typedef _Float16 half8 __attribute__((ext_vector_type(8)));
typedef float floatx4 __attribute__((ext_vector_type(4)));

// ---------------- Graph build (zero global atomics) ----------------
// k_count: ONE packed u32 LDS histogram (in_deg low16 | out_deg high16) ->
// SEGN=25000 with NSEG=4: edge arrays re-read 4x not 8x (51 MB total).

__global__ __launch_bounds__(512) void k_count(const int* __restrict__ src, const int* __restrict__ dst,
                                               unsigned char* __restrict__ cnt_out,
                                               unsigned char* __restrict__ cnt_in) {
    __shared__ unsigned pk[SEGN];            // 100 KB
    const int c = blockIdx.x;
    const int lo = blockIdx.y * SEGN;
    for (int i = threadIdx.x; i < SEGN; i += 512) pk[i] = 0;
    __syncthreads();
    const int4* s4 = (const int4*)(src + c * CH);
    const int4* d4 = (const int4*)(dst + c * CH);
    for (int i = threadIdx.x; i < CH / 4; i += 512) {
        int4 s = s4[i], d = d4[i];
        unsigned a;
        a = (unsigned)(s.x - lo); if (a < SEGN) atomicAdd(&pk[a], 0x10000u);
        a = (unsigned)(s.y - lo); if (a < SEGN) atomicAdd(&pk[a], 0x10000u);
        a = (unsigned)(s.z - lo); if (a < SEGN) atomicAdd(&pk[a], 0x10000u);
        a = (unsigned)(s.w - lo); if (a < SEGN) atomicAdd(&pk[a], 0x10000u);
        a = (unsigned)(d.x - lo); if (a < SEGN) atomicAdd(&pk[a], 1u);
        a = (unsigned)(d.y - lo); if (a < SEGN) atomicAdd(&pk[a], 1u);
        a = (unsigned)(d.z - lo); if (a < SEGN) atomicAdd(&pk[a], 1u);
        a = (unsigned)(d.w - lo); if (a < SEGN) atomicAdd(&pk[a], 1u);
    }
    __syncthreads();
    for (int i = threadIdx.x; i < SEGN; i += 512) {
        unsigned v = pk[i];
        cnt_in [c * N_NODES + lo + i] = (unsigned char)(v & 0xFFFF);
        cnt_out[c * N_NODES + lo + i] = (unsigned char)(v >> 16);
    }
}

__global__ __launch_bounds__(256) void k_scan(unsigned char* __restrict__ cnt_in,
                                              const unsigned char* __restrict__ cnt_out,
                                              int* __restrict__ fill, float* __restrict__ norm_src,
                                              float* __restrict__ norm_dst) {
    int d = blockIdx.x * 256 + threadIdx.x;
    if (d >= N_NODES) return;
    int run = 0;
    for (int c = 0; c < NCHUNK; ++c) {
        int v = cnt_in[c * N_NODES + d];
        cnt_in[c * N_NODES + d] = (unsigned char)run;   // deg fits u8
        run += v;
    }
    int od = 0;
    for (int c = 0; c < NCHUNK; ++c) od += cnt_out[c * N_NODES + d];
    fill[d] = run;
    norm_dst[d] = rsqrtf((float)(run < 1 ? 1 : run));
    norm_src[d] = rsqrtf((float)(od  < 1 ? 1 : od ));
}

// k_scatter: u16-packed slot counters (50 KB LDS at SEGN=25000), LDS atomics only.
__global__ __launch_bounds__(512) void k_scatter(const int* __restrict__ src, const int* __restrict__ dst,
                                                 const unsigned char* __restrict__ bases,
                                                 int* __restrict__ ell) {
    __shared__ unsigned base[SEGN / 2];      // u16 pairs
    const int c = blockIdx.x;
    const int lo = blockIdx.y * SEGN;
    for (int i = threadIdx.x; i < SEGN / 2; i += 512) {
        unsigned b0 = bases[c * N_NODES + lo + 2 * i];
        unsigned b1 = bases[c * N_NODES + lo + 2 * i + 1];
        base[i] = b0 | (b1 << 16);
    }
    __syncthreads();
    const int4* s4 = (const int4*)(src + c * CH);
    const int4* d4 = (const int4*)(dst + c * CH);
    for (int i = threadIdx.x; i < CH / 4; i += 512) {
        int4 s = s4[i], d = d4[i];
        unsigned r, sh, old; int p;
        r = (unsigned)(d.x - lo); if (r < SEGN) { sh = (r & 1) << 4; old = atomicAdd(&base[r >> 1], 1u << sh); p = (old >> sh) & 0xFFFF; if (p < ELL_W) ell[p * N_NODES + lo + r] = s.x; }
        r = (unsigned)(d.y - lo); if (r < SEGN) { sh = (r & 1) << 4; old = atomicAdd(&base[r >> 1], 1u << sh); p = (old >> sh) & 0xFFFF; if (p < ELL_W) ell[p * N_NODES + lo + r] = s.y; }
        r = (unsigned)(d.z - lo); if (r < SEGN) { sh = (r & 1) << 4; old = atomicAdd(&base[r >> 1], 1u << sh); p = (old >> sh) & 0xFFFF; if (p < ELL_W) ell[p * N_NODES + lo + r] = s.z; }
        r = (unsigned)(d.w - lo); if (r < SEGN) { sh = (r & 1) << 4; old = atomicAdd(&base[r >> 1], 1u << sh); p = (old >> sh) & 0xFFFF; if (p < ELL_W) ell[p * N_NODES + lo + r] = s.w; }
    }
}

// ---------------- accumulate helper ----------------
__device__ __forceinline__ void acc16B(const float4& v, float* acc) {
    const __half2* hh = (const __half2*)&v;
    #pragma unroll
    for (int t = 0; t < 4; ++t) {
        float2 f = __half22float2(hh[t]);
        acc[2 * t + 0] += f.x;
        acc[2 * t + 1] += f.y;
    }
}

// ---------------- MFMA GEMM (layer 0): Y(fp16) = norm .* (X_fp32 @ W) ----------------
template<int K, int NCOL>
__global__ __launch_bounds__(256) void k_gemm(const float* __restrict__ Xv, const float* __restrict__ W,
                                              const float* __restrict__ norm, __half* __restrict__ Y) {
    constexpr int NT = (NCOL + 15) / 16;
    constexpr int NR = NT * 16;
    __shared__ __align__(16) _Float16 Xh[64][K + 8];
    __shared__ __align__(16) _Float16 Wt[NR][K + 8];
    const int tid = threadIdx.x;
    const int row0 = blockIdx.x * 64;

    for (int idx = tid; idx < K * NCOL; idx += 256) {
        int k = idx / NCOL, c = idx - (idx / NCOL) * NCOL;
        Wt[c][k] = (_Float16)W[idx];
    }
    for (int idx = tid; idx < (NR - NCOL) * K; idx += 256) {
        int c = NCOL + idx / K, k = idx - (idx / K) * K;
        Wt[c][k] = (_Float16)0;
    }

    for (int idx = tid; idx < 64 * (K / 8); idx += 256) {
        int r = idx / (K / 8), kc = idx - (idx / (K / 8)) * (K / 8);
        int gr = row0 + r;
        half8 v = {0, 0, 0, 0, 0, 0, 0, 0};
        if (gr < N_NODES) {
            const float* X = Xv + (long)gr * K + kc * 8;
            float4 u0 = *(const float4*)(X + 0);
            float4 u1 = *(const float4*)(X + 4);
            v.s0 = (_Float16)u0.x; v.s1 = (_Float16)u0.y;
            v.s2 = (_Float16)u0.z; v.s3 = (_Float16)u0.w;
            v.s4 = (_Float16)u1.x; v.s5 = (_Float16)u1.y;
            v.s6 = (_Float16)u1.z; v.s7 = (_Float16)u1.w;
        }
        *(half8*)&Xh[r][kc * 8] = v;
    }
    __syncthreads();

    const int lane = tid & 63;
    const int wave = tid >> 6;
    const int quad = lane >> 4;
    const int l16 = lane & 15;
    const int r0 = wave * 16;

    floatx4 acc[NT] = {};
    #pragma unroll
    for (int k0 = 0; k0 < K; k0 += 32) {
        half8 a = *(const half8*)&Xh[r0 + l16][k0 + quad * 8];
        #pragma unroll
        for (int t = 0; t < NT; ++t) {
            half8 b = *(const half8*)&Wt[t * 16 + l16][k0 + quad * 8];
            acc[t] = __builtin_amdgcn_mfma_f32_16x16x32_f16(a, b, acc[t], 0, 0, 0);
        }
    }

    #pragma unroll
    for (int i = 0; i < 4; ++i) {
        int gr = row0 + r0 + quad * 4 + i;
        if (gr < N_NODES) {
            float s = norm[gr];
            #pragma unroll
            for (int t = 0; t < NT; ++t) {
                int c = t * 16 + l16;
                if (c < NCOL) Y[(long)gr * NCOL + c] = __float2half(acc[t][i] * s);
            }
        }
    }
}

// ---------------- Fused agg + GEMM (LDS indices, double-buffered x8 gather) ----------------
template<int K, int NCOL>
__global__ __launch_bounds__(256) void k_agg_gemm(const __half* __restrict__ XWp, const int* __restrict__ ell,
                                                  const int* __restrict__ deg, const float* __restrict__ norm_dst,
                                                  const float* __restrict__ biasp, const float* __restrict__ W,
                                                  const float* __restrict__ norm, __half* __restrict__ Y) {
    constexpr int NT = (NCOL + 15) / 16;
    constexpr int NR = NT * 16;
    constexpr int NQ = K / 8;
    __shared__ __align__(16) _Float16 Xh[64][K + 8];
    __shared__ __align__(16) _Float16 Wt[NR][K + 8];
    __shared__ int sIdx[64][65];
    __shared__ int sDeg[64];
    __shared__ int sMax;
    const int tid = threadIdx.x;
    const int row0 = blockIdx.x * 64;

    for (int idx = tid; idx < K * NCOL; idx += 256) {
        int k = idx / NCOL, c = idx - (idx / NCOL) * NCOL;
        Wt[c][k] = (_Float16)W[idx];
    }
    for (int idx = tid; idx < (NR - NCOL) * K; idx += 256) {
        int c = NCOL + idx / K, k = idx - (idx / K) * K;
        Wt[c][k] = (_Float16)0;
    }

    if (tid < 64) {
        int node = row0 + tid;
        int dg = 0;
        if (node < N_NODES) { dg = deg[node]; if (dg > ELL_W) dg = ELL_W; }
        sDeg[tid] = dg;
        int v = dg;
        #pragma unroll
        for (int o = 32; o > 0; o >>= 1) v = max(v, __shfl_down(v, o));
        if (tid == 0) sMax = v;
    }
    __syncthreads();
    const int mdeg = sMax;
    for (int i = tid; i < mdeg * 64; i += 256) {
        int slot = i >> 6, r = i & 63;
        int node = row0 + r;
        sIdx[r][slot] = (node < N_NODES) ? ell[slot * N_NODES + node] : 0;
    }
    __syncthreads();

    // Phase 1: aggregate into Xh; double-buffered 8-deep gather pipeline.
    for (int item = tid; item < 64 * NQ; item += 256) {
        int r = item / NQ, q = item - (item / NQ) * NQ;
        int d = row0 + r;
        int dg = sDeg[r];
        const int* idxr = sIdx[r];
        float acc[8] = {};
        int j = 0;
        if (dg >= 8) {
            float4 va[8], vb[8];
            #pragma unroll
            for (int u = 0; u < 8; ++u) va[u] = *(const float4*)(XWp + (long)idxr[u] * K + q * 8);
            j = 8;
            for (;;) {
                if (j + 8 <= dg) {
                    #pragma unroll
                    for (int u = 0; u < 8; ++u) vb[u] = *(const float4*)(XWp + (long)idxr[j + u] * K + q * 8);
                    #pragma unroll
                    for (int u = 0; u < 8; ++u) acc16B(va[u], acc);
                    j += 8;
                } else {
                    #pragma unroll
                    for (int u = 0; u < 8; ++u) acc16B(va[u], acc);
                    break;
                }
                if (j + 8 <= dg) {
                    #pragma unroll
                    for (int u = 0; u < 8; ++u) va[u] = *(const float4*)(XWp + (long)idxr[j + u] * K + q * 8);
                    #pragma unroll
                    for (int u = 0; u < 8; ++u) acc16B(vb[u], acc);
                    j += 8;
                } else {
                    #pragma unroll
                    for (int u = 0; u < 8; ++u) acc16B(vb[u], acc);
                    break;
                }
            }
        }
        for (; j < dg; ++j) {
            float4 rv = *(const float4*)(XWp + (long)idxr[j] * K + q * 8);
            acc16B(rv, acc);
        }
        _Float16 res[8] = {};
        if (d < N_NODES) {
            float nd = norm_dst[d];
            #pragma unroll
            for (int t = 0; t < 8; ++t) {
                float o = acc[t] * nd + biasp[q * 8 + t];
                res[t] = (_Float16)fmaxf(o, 0.f);
            }
        }
        *(half8*)&Xh[r][q * 8] = *(const half8*)res;
    }
    __syncthreads();

    const int lane = tid & 63;
    const int wave = tid >> 6;
    const int quad = lane >> 4;
    const int l16 = lane & 15;
    const int r0 = wave * 16;

    floatx4 acc[NT] = {};
    #pragma unroll
    for (int k0 = 0; k0 < K; k0 += 32) {
        half8 a = *(const half8*)&Xh[r0 + l16][k0 + quad * 8];
        #pragma unroll
        for (int t = 0; t < NT; ++t) {
            half8 b = *(const half8*)&Wt[t * 16 + l16][k0 + quad * 8];
            acc[t] = __builtin_amdgcn_mfma_f32_16x16x32_f16(a, b, acc[t], 0, 0, 0);
        }
    }

    #pragma unroll
    for (int i = 0; i < 4; ++i) {
        int gr = row0 + r0 + quad * 4 + i;
        if (gr < N_NODES) {
            float s = norm[gr];
            #pragma unroll
            for (int t = 0; t < NT; ++t) {
                int c = t * 16 + l16;
                if (c < NCOL) Y[(long)gr * NCOL + c] = __float2half(acc[t][i] * s);
            }
        }
    }
}

// ---------------- Final aggregation (LDS indices, pipelined, fp32 out) ----------------
template<int NF>
__global__ __launch_bounds__(320) void k_agg_f(const __half* __restrict__ XW, const int* __restrict__ ell,
                                               const int* __restrict__ deg, const float* __restrict__ norm_dst,
                                               const float* __restrict__ bias, float* __restrict__ OUT) {
    constexpr int NQ = NF / 8;   // 5
    __shared__ int sIdx[64][65];
    __shared__ int sDeg[64];
    __shared__ int sMax;
    const int tid = threadIdx.x;
    const int row0 = blockIdx.x * 64;

    if (tid < 64) {
        int node = row0 + tid;
        int dg = 0;
        if (node < N_NODES) { dg = deg[node]; if (dg > ELL_W) dg = ELL_W; }
        sDeg[tid] = dg;
        int v = dg;
        #pragma unroll
        for (int o = 32; o > 0; o >>= 1) v = max(v, __shfl_down(v, o));
        if (tid == 0) sMax = v;
    }
    __syncthreads();
    const int mdeg = sMax;
    for (int i = tid; i < mdeg * 64; i += 320) {
        int slot = i >> 6, r = i & 63;
        int node = row0 + r;
        sIdx[r][slot] = (node < N_NODES) ? ell[slot * N_NODES + node] : 0;
    }
    __syncthreads();

    const int r = tid / NQ, q = tid - (tid / NQ) * NQ;
    const int d = row0 + r;
    if (d >= N_NODES) return;
    const int dg = sDeg[r];
    const int* idxr = sIdx[r];

    float acc[8] = {};
    int j = 0;
    if (dg >= 8) {
        float4 va[8], vb[8];
        #pragma unroll
        for (int u = 0; u < 8; ++u) va[u] = *(const float4*)(XW + (long)idxr[u] * NF + q * 8);
        j = 8;
        for (;;) {
            if (j + 8 <= dg) {
                #pragma unroll
                for (int u = 0; u < 8; ++u) vb[u] = *(const float4*)(XW + (long)idxr[j + u] * NF + q * 8);
                #pragma unroll
                for (int u = 0; u < 8; ++u) acc16B(va[u], acc);
                j += 8;
            } else {
                #pragma unroll
                for (int u = 0; u < 8; ++u) acc16B(va[u], acc);
                break;
            }
            if (j + 8 <= dg) {
                #pragma unroll
                for (int u = 0; u < 8; ++u) va[u] = *(const float4*)(XW + (long)idxr[j + u] * NF + q * 8);
                #pragma unroll
                for (int u = 0; u < 8; ++u) acc16B(vb[u], acc);
                j += 8;
            } else {
                #pragma unroll
                for (int u = 0; u < 8; ++u) acc16B(vb[u], acc);
                break;
            }
        }
    }
    for (; j < dg; ++j) {
        float4 rv = *(const float4*)(XW + (long)idxr[j] * NF + q * 8);
        acc16B(rv, acc);
    }

    float nd = norm_dst[d];
    float o[8];
    #pragma unroll
    for (int t = 0; t < 8; ++t) o[t] = acc[t] * nd + bias[q * 8 + t];
    *(float4*)(OUT + (long)d * NF + q * 8 + 0) = make_float4(o[0], o[1], o[2], o[3]);
    *(float4*)(OUT + (long)d * NF + q * 8 + 4) = make_float4(o[4], o[5], o[6], o[7]);
}

extern "C" void kernel_launch(void* const* d_in, const int* in_sizes, int n_in,
                              void* d_out, int out_size, void* d_ws, size_t ws_size,
                              hipStream_t stream) {
    const float* h  = (const float*)d_in[0];
    const float* W0 = (const float*)d_in[1];
    const float* b0 = (const float*)d_in[2];
    const float* W1 = (const float*)d_in[3];
    const float* b1 = (const float*)d_in[4];
    const float* W2 = (const float*)d_in[5];
    const float* b2 = (const float*)d_in[6];
    const int* src  = (const int*)d_in[7];
    const int* dst  = (const int*)d_in[8];
    float* out = (float*)d_out;

    char* ws = (char*)d_ws;
    size_t off = 0;
    int* fill        = (int*)(ws + off); off += (size_t)N_NODES * 4;
    float* norm_src  = (float*)(ws + off); off += (size_t)N_NODES * 4;
    float* norm_dst  = (float*)(ws + off); off += (size_t)N_NODES * 4;
    int* ell         = (int*)(ws + off); off += (size_t)N_NODES * ELL_W * 4;   // [ELL_W][N_NODES]
    unsigned char* cnt_in  = (unsigned char*)(ws + off); off += (size_t)NCHUNK * N_NODES; // 6.4 MB
    unsigned char* cnt_out = (unsigned char*)(ws + off); off += (size_t)NCHUNK * N_NODES; // 6.4 MB
    __half* bufA  = (__half*)(ws + off); off += (size_t)N_NODES * 64 * 2;      // 12.8 MB ping
    __half* bufB  = (__half*)(ws + off); off += (size_t)N_NODES * 64 * 2;      // 12.8 MB pong

    // Build (zero global atomics):
    k_count<<<dim3(NCHUNK, NSEG), 512, 0, stream>>>(src, dst, cnt_out, cnt_in);
    k_scan<<<(N_NODES + 255) / 256, 256, 0, stream>>>(cnt_in, cnt_out, fill, norm_src, norm_dst);
    k_scatter<<<dim3(NCHUNK, NSEG), 512, 0, stream>>>(src, dst, cnt_in, ell);

    const int grid = (N_NODES + 63) / 64;

    // Layer 0 GEMM: h(fp32) @ W0 -> bufA = XW0 (fp16)
    k_gemm<128, 64><<<grid, 256, 0, stream>>>(h, W0, norm_src, bufA);
    // Fused: act1 = relu(agg(XW0)*nd + b0);  bufB = (act1 @ W1) * norm_src  (fp16)
    k_agg_gemm<64, 64><<<grid, 256, 0, stream>>>(bufA, ell, fill, norm_dst, b0, W1, norm_src, bufB);
    // Fused: act2 = relu(agg(XW1)*nd + b1);  bufA = (act2 @ W2) * norm_src  (fp16, 40-wide)
    k_agg_gemm<64, 40><<<grid, 256, 0, stream>>>(bufB, ell, fill, norm_dst, b1, W2, norm_src, bufA);
    // Final: out = agg(XW2)*nd + b2  (fp32)
    k_agg_f<40><<<grid, 320, 0, stream>>>(bufA, ell, fill, norm_dst, b2, out);
}

// Round 12
// 272.933 us; speedup vs baseline: 1.0988x; 1.0988x over previous
//
#include <hip/hip_runtime.h>
#include <hip/hip_fp16.h>

#define N_NODES 100000
#define N_EDGES 1600000
#define ELL_W 64
#define NCHUNK 64                  // edge chunks
#define NSEG 4                     // node segments
#define CH (N_EDGES / NCHUNK)      // 25000 edges per chunk
#define SEGN (N_NODES / NSEG)      // 25000 nodes per segment

typedef _Float16 half8 __attribute__((ext_vector_type(8)));
typedef float floatx4 __attribute__((ext_vector_type(4)));

// ---------------- Graph build (zero global atomics) ----------------
// k_count: ONE packed u32 LDS histogram (in_deg low16 | out_deg high16);
// NSEG=4 -> edge arrays re-read 4x not 8x. Grid = 256 blocks = 1/CU, so the
// 100 KB LDS does not cost occupancy.

__global__ __launch_bounds__(512) void k_count(const int* __restrict__ src, const int* __restrict__ dst,
                                               unsigned char* __restrict__ cnt_out,
                                               unsigned char* __restrict__ cnt_in) {
    __shared__ unsigned pk[SEGN];            // 100 KB
    const int c = blockIdx.x;
    const int lo = blockIdx.y * SEGN;
    for (int i = threadIdx.x; i < SEGN; i += 512) pk[i] = 0;
    __syncthreads();
    const int4* s4 = (const int4*)(src + c * CH);
    const int4* d4 = (const int4*)(dst + c * CH);
    for (int i = threadIdx.x; i < CH / 4; i += 512) {
        int4 s = s4[i], d = d4[i];
        unsigned a;
        a = (unsigned)(s.x - lo); if (a < SEGN) atomicAdd(&pk[a], 0x10000u);
        a = (unsigned)(s.y - lo); if (a < SEGN) atomicAdd(&pk[a], 0x10000u);
        a = (unsigned)(s.z - lo); if (a < SEGN) atomicAdd(&pk[a], 0x10000u);
        a = (unsigned)(s.w - lo); if (a < SEGN) atomicAdd(&pk[a], 0x10000u);
        a = (unsigned)(d.x - lo); if (a < SEGN) atomicAdd(&pk[a], 1u);
        a = (unsigned)(d.y - lo); if (a < SEGN) atomicAdd(&pk[a], 1u);
        a = (unsigned)(d.z - lo); if (a < SEGN) atomicAdd(&pk[a], 1u);
        a = (unsigned)(d.w - lo); if (a < SEGN) atomicAdd(&pk[a], 1u);
    }
    __syncthreads();
    for (int i = threadIdx.x; i < SEGN; i += 512) {
        unsigned v = pk[i];
        cnt_in [c * N_NODES + lo + i] = (unsigned char)(v & 0xFFFF);
        cnt_out[c * N_NODES + lo + i] = (unsigned char)(v >> 16);
    }
}

__global__ __launch_bounds__(256) void k_scan(unsigned char* __restrict__ cnt_in,
                                              const unsigned char* __restrict__ cnt_out,
                                              int* __restrict__ fill, float* __restrict__ norm_src,
                                              float* __restrict__ norm_dst) {
    int d = blockIdx.x * 256 + threadIdx.x;
    if (d >= N_NODES) return;
    int run = 0;
    for (int c = 0; c < NCHUNK; ++c) {
        int v = cnt_in[c * N_NODES + d];
        cnt_in[c * N_NODES + d] = (unsigned char)run;   // deg fits u8
        run += v;
    }
    int od = 0;
    for (int c = 0; c < NCHUNK; ++c) od += cnt_out[c * N_NODES + d];
    fill[d] = run;
    norm_dst[d] = rsqrtf((float)(run < 1 ? 1 : run));
    norm_src[d] = rsqrtf((float)(od  < 1 ? 1 : od ));
}

// k_scatter: u16-packed slot counters (50 KB LDS), LDS atomics only.
__global__ __launch_bounds__(512) void k_scatter(const int* __restrict__ src, const int* __restrict__ dst,
                                                 const unsigned char* __restrict__ bases,
                                                 int* __restrict__ ell) {
    __shared__ unsigned base[SEGN / 2];      // u16 pairs
    const int c = blockIdx.x;
    const int lo = blockIdx.y * SEGN;
    for (int i = threadIdx.x; i < SEGN / 2; i += 512) {
        unsigned b0 = bases[c * N_NODES + lo + 2 * i];
        unsigned b1 = bases[c * N_NODES + lo + 2 * i + 1];
        base[i] = b0 | (b1 << 16);
    }
    __syncthreads();
    const int4* s4 = (const int4*)(src + c * CH);
    const int4* d4 = (const int4*)(dst + c * CH);
    for (int i = threadIdx.x; i < CH / 4; i += 512) {
        int4 s = s4[i], d = d4[i];
        unsigned r, sh, old; int p;
        r = (unsigned)(d.x - lo); if (r < SEGN) { sh = (r & 1) << 4; old = atomicAdd(&base[r >> 1], 1u << sh); p = (old >> sh) & 0xFFFF; if (p < ELL_W) ell[p * N_NODES + lo + r] = s.x; }
        r = (unsigned)(d.y - lo); if (r < SEGN) { sh = (r & 1) << 4; old = atomicAdd(&base[r >> 1], 1u << sh); p = (old >> sh) & 0xFFFF; if (p < ELL_W) ell[p * N_NODES + lo + r] = s.y; }
        r = (unsigned)(d.z - lo); if (r < SEGN) { sh = (r & 1) << 4; old = atomicAdd(&base[r >> 1], 1u << sh); p = (old >> sh) & 0xFFFF; if (p < ELL_W) ell[p * N_NODES + lo + r] = s.z; }
        r = (unsigned)(d.w - lo); if (r < SEGN) { sh = (r & 1) << 4; old = atomicAdd(&base[r >> 1], 1u << sh); p = (old >> sh) & 0xFFFF; if (p < ELL_W) ell[p * N_NODES + lo + r] = s.w; }
    }
}

// ---------------- accumulate helper ----------------
__device__ __forceinline__ void acc16B(const float4& v, float* acc) {
    const __half2* hh = (const __half2*)&v;
    #pragma unroll
    for (int t = 0; t < 4; ++t) {
        float2 f = __half22float2(hh[t]);
        acc[2 * t + 0] += f.x;
        acc[2 * t + 1] += f.y;
    }
}

// ---------------- MFMA GEMM (layer 0): Y(fp16) = norm .* (X_fp32 @ W) ----------------
template<int K, int NCOL>
__global__ __launch_bounds__(256) void k_gemm(const float* __restrict__ Xv, const float* __restrict__ W,
                                              const float* __restrict__ norm, __half* __restrict__ Y) {
    constexpr int NT = (NCOL + 15) / 16;
    constexpr int NR = NT * 16;
    __shared__ __align__(16) _Float16 Xh[64][K + 8];
    __shared__ __align__(16) _Float16 Wt[NR][K + 8];
    const int tid = threadIdx.x;
    const int row0 = blockIdx.x * 64;

    for (int idx = tid; idx < K * NCOL; idx += 256) {
        int k = idx / NCOL, c = idx - (idx / NCOL) * NCOL;
        Wt[c][k] = (_Float16)W[idx];
    }
    for (int idx = tid; idx < (NR - NCOL) * K; idx += 256) {
        int c = NCOL + idx / K, k = idx - (idx / K) * K;
        Wt[c][k] = (_Float16)0;
    }

    for (int idx = tid; idx < 64 * (K / 8); idx += 256) {
        int r = idx / (K / 8), kc = idx - (idx / (K / 8)) * (K / 8);
        int gr = row0 + r;
        half8 v = {0, 0, 0, 0, 0, 0, 0, 0};
        if (gr < N_NODES) {
            const float* X = Xv + (long)gr * K + kc * 8;
            float4 u0 = *(const float4*)(X + 0);
            float4 u1 = *(const float4*)(X + 4);
            v.s0 = (_Float16)u0.x; v.s1 = (_Float16)u0.y;
            v.s2 = (_Float16)u0.z; v.s3 = (_Float16)u0.w;
            v.s4 = (_Float16)u1.x; v.s5 = (_Float16)u1.y;
            v.s6 = (_Float16)u1.z; v.s7 = (_Float16)u1.w;
        }
        *(half8*)&Xh[r][kc * 8] = v;
    }
    __syncthreads();

    const int lane = tid & 63;
    const int wave = tid >> 6;
    const int quad = lane >> 4;
    const int l16 = lane & 15;
    const int r0 = wave * 16;

    floatx4 acc[NT] = {};
    #pragma unroll
    for (int k0 = 0; k0 < K; k0 += 32) {
        half8 a = *(const half8*)&Xh[r0 + l16][k0 + quad * 8];
        #pragma unroll
        for (int t = 0; t < NT; ++t) {
            half8 b = *(const half8*)&Wt[t * 16 + l16][k0 + quad * 8];
            acc[t] = __builtin_amdgcn_mfma_f32_16x16x32_f16(a, b, acc[t], 0, 0, 0);
        }
    }

    #pragma unroll
    for (int i = 0; i < 4; ++i) {
        int gr = row0 + r0 + quad * 4 + i;
        if (gr < N_NODES) {
            float s = norm[gr];
            #pragma unroll
            for (int t = 0; t < NT; ++t) {
                int c = t * 16 + l16;
                if (c < NCOL) Y[(long)gr * NCOL + c] = __float2half(acc[t][i] * s);
            }
        }
    }
}

// ---------------- Fused agg + GEMM (LDS indices, simple x8 gather batch) ----------------
template<int K, int NCOL>
__global__ __launch_bounds__(256) void k_agg_gemm(const __half* __restrict__ XWp, const int* __restrict__ ell,
                                                  const int* __restrict__ deg, const float* __restrict__ norm_dst,
                                                  const float* __restrict__ biasp, const float* __restrict__ W,
                                                  const float* __restrict__ norm, __half* __restrict__ Y) {
    constexpr int NT = (NCOL + 15) / 16;
    constexpr int NR = NT * 16;
    constexpr int NQ = K / 8;
    __shared__ __align__(16) _Float16 Xh[64][K + 8];
    __shared__ __align__(16) _Float16 Wt[NR][K + 8];
    __shared__ int sIdx[64][65];
    __shared__ int sDeg[64];
    __shared__ int sMax;
    const int tid = threadIdx.x;
    const int row0 = blockIdx.x * 64;

    for (int idx = tid; idx < K * NCOL; idx += 256) {
        int k = idx / NCOL, c = idx - (idx / NCOL) * NCOL;
        Wt[c][k] = (_Float16)W[idx];
    }
    for (int idx = tid; idx < (NR - NCOL) * K; idx += 256) {
        int c = NCOL + idx / K, k = idx - (idx / K) * K;
        Wt[c][k] = (_Float16)0;
    }

    if (tid < 64) {
        int node = row0 + tid;
        int dg = 0;
        if (node < N_NODES) { dg = deg[node]; if (dg > ELL_W) dg = ELL_W; }
        sDeg[tid] = dg;
        int v = dg;
        #pragma unroll
        for (int o = 32; o > 0; o >>= 1) v = max(v, __shfl_down(v, o));
        if (tid == 0) sMax = v;
    }
    __syncthreads();
    const int mdeg = sMax;
    for (int i = tid; i < mdeg * 64; i += 256) {
        int slot = i >> 6, r = i & 63;
        int node = row0 + r;
        sIdx[r][slot] = (node < N_NODES) ? ell[slot * N_NODES + node] : 0;
    }
    __syncthreads();

    // Phase 1: aggregate into Xh (prev epilogue: *norm_dst + biasp, ReLU).
    for (int item = tid; item < 64 * NQ; item += 256) {
        int r = item / NQ, q = item - (item / NQ) * NQ;
        int d = row0 + r;
        int dg = sDeg[r];
        const int* idxr = sIdx[r];
        float acc[8] = {};
        int j = 0;
        for (; j + 8 <= dg; j += 8) {
            float4 v[8];
            #pragma unroll
            for (int u = 0; u < 8; ++u)
                v[u] = *(const float4*)(XWp + (long)idxr[j + u] * K + q * 8);
            #pragma unroll
            for (int u = 0; u < 8; ++u) acc16B(v[u], acc);
        }
        for (; j < dg; ++j) {
            float4 rv = *(const float4*)(XWp + (long)idxr[j] * K + q * 8);
            acc16B(rv, acc);
        }
        _Float16 res[8] = {};
        if (d < N_NODES) {
            float nd = norm_dst[d];
            #pragma unroll
            for (int t = 0; t < 8; ++t) {
                float o = acc[t] * nd + biasp[q * 8 + t];
                res[t] = (_Float16)fmaxf(o, 0.f);
            }
        }
        *(half8*)&Xh[r][q * 8] = *(const half8*)res;
    }
    __syncthreads();

    const int lane = tid & 63;
    const int wave = tid >> 6;
    const int quad = lane >> 4;
    const int l16 = lane & 15;
    const int r0 = wave * 16;

    floatx4 acc[NT] = {};
    #pragma unroll
    for (int k0 = 0; k0 < K; k0 += 32) {
        half8 a = *(const half8*)&Xh[r0 + l16][k0 + quad * 8];
        #pragma unroll
        for (int t = 0; t < NT; ++t) {
            half8 b = *(const half8*)&Wt[t * 16 + l16][k0 + quad * 8];
            acc[t] = __builtin_amdgcn_mfma_f32_16x16x32_f16(a, b, acc[t], 0, 0, 0);
        }
    }

    #pragma unroll
    for (int i = 0; i < 4; ++i) {
        int gr = row0 + r0 + quad * 4 + i;
        if (gr < N_NODES) {
            float s = norm[gr];
            #pragma unroll
            for (int t = 0; t < NT; ++t) {
                int c = t * 16 + l16;
                if (c < NCOL) Y[(long)gr * NCOL + c] = __float2half(acc[t][i] * s);
            }
        }
    }
}

// ---------------- Final aggregation (LDS indices, x8 batch, fp32 out) ----------------
template<int NF>
__global__ __launch_bounds__(320) void k_agg_f(const __half* __restrict__ XW, const int* __restrict__ ell,
                                               const int* __restrict__ deg, const float* __restrict__ norm_dst,
                                               const float* __restrict__ bias, float* __restrict__ OUT) {
    constexpr int NQ = NF / 8;   // 5
    __shared__ int sIdx[64][65];
    __shared__ int sDeg[64];
    __shared__ int sMax;
    const int tid = threadIdx.x;
    const int row0 = blockIdx.x * 64;

    if (tid < 64) {
        int node = row0 + tid;
        int dg = 0;
        if (node < N_NODES) { dg = deg[node]; if (dg > ELL_W) dg = ELL_W; }
        sDeg[tid] = dg;
        int v = dg;
        #pragma unroll
        for (int o = 32; o > 0; o >>= 1) v = max(v, __shfl_down(v, o));
        if (tid == 0) sMax = v;
    }
    __syncthreads();
    const int mdeg = sMax;
    for (int i = tid; i < mdeg * 64; i += 320) {
        int slot = i >> 6, r = i & 63;
        int node = row0 + r;
        sIdx[r][slot] = (node < N_NODES) ? ell[slot * N_NODES + node] : 0;
    }
    __syncthreads();

    const int r = tid / NQ, q = tid - (tid / NQ) * NQ;
    const int d = row0 + r;
    if (d >= N_NODES) return;
    const int dg = sDeg[r];
    const int* idxr = sIdx[r];

    float acc[8] = {};
    int j = 0;
    for (; j + 8 <= dg; j += 8) {
        float4 v[8];
        #pragma unroll
        for (int u = 0; u < 8; ++u)
            v[u] = *(const float4*)(XW + (long)idxr[j + u] * NF + q * 8);
        #pragma unroll
        for (int u = 0; u < 8; ++u) acc16B(v[u], acc);
    }
    for (; j < dg; ++j) {
        float4 rv = *(const float4*)(XW + (long)idxr[j] * NF + q * 8);
        acc16B(rv, acc);
    }

    float nd = norm_dst[d];
    float o[8];
    #pragma unroll
    for (int t = 0; t < 8; ++t) o[t] = acc[t] * nd + bias[q * 8 + t];
    *(float4*)(OUT + (long)d * NF + q * 8 + 0) = make_float4(o[0], o[1], o[2], o[3]);
    *(float4*)(OUT + (long)d * NF + q * 8 + 4) = make_float4(o[4], o[5], o[6], o[7]);
}

extern "C" void kernel_launch(void* const* d_in, const int* in_sizes, int n_in,
                              void* d_out, int out_size, void* d_ws, size_t ws_size,
                              hipStream_t stream) {
    const float* h  = (const float*)d_in[0];
    const float* W0 = (const float*)d_in[1];
    const float* b0 = (const float*)d_in[2];
    const float* W1 = (const float*)d_in[3];
    const float* b1 = (const float*)d_in[4];
    const float* W2 = (const float*)d_in[5];
    const float* b2 = (const float*)d_in[6];
    const int* src  = (const int*)d_in[7];
    const int* dst  = (const int*)d_in[8];
    float* out = (float*)d_out;

    char* ws = (char*)d_ws;
    size_t off = 0;
    int* fill        = (int*)(ws + off); off += (size_t)N_NODES * 4;
    float* norm_src  = (float*)(ws + off); off += (size_t)N_NODES * 4;
    float* norm_dst  = (float*)(ws + off); off += (size_t)N_NODES * 4;
    int* ell         = (int*)(ws + off); off += (size_t)N_NODES * ELL_W * 4;   // [ELL_W][N_NODES]
    unsigned char* cnt_in  = (unsigned char*)(ws + off); off += (size_t)NCHUNK * N_NODES; // 6.4 MB
    unsigned char* cnt_out = (unsigned char*)(ws + off); off += (size_t)NCHUNK * N_NODES; // 6.4 MB
    __half* bufA  = (__half*)(ws + off); off += (size_t)N_NODES * 64 * 2;      // 12.8 MB ping
    __half* bufB  = (__half*)(ws + off); off += (size_t)N_NODES * 64 * 2;      // 12.8 MB pong

    // Build (zero global atomics):
    k_count<<<dim3(NCHUNK, NSEG), 512, 0, stream>>>(src, dst, cnt_out, cnt_in);
    k_scan<<<(N_NODES + 255) / 256, 256, 0, stream>>>(cnt_in, cnt_out, fill, norm_src, norm_dst);
    k_scatter<<<dim3(NCHUNK, NSEG), 512, 0, stream>>>(src, dst, cnt_in, ell);

    const int grid = (N_NODES + 63) / 64;

    // Layer 0 GEMM: h(fp32) @ W0 -> bufA = XW0 (fp16)
    k_gemm<128, 64><<<grid, 256, 0, stream>>>(h, W0, norm_src, bufA);
    // Fused: act1 = relu(agg(XW0)*nd + b0);  bufB = (act1 @ W1) * norm_src  (fp16)
    k_agg_gemm<64, 64><<<grid, 256, 0, stream>>>(bufA, ell, fill, norm_dst, b0, W1, norm_src, bufB);
    // Fused: act2 = relu(agg(XW1)*nd + b1);  bufA = (act2 @ W2) * norm_src  (fp16, 40-wide)
    k_agg_gemm<64, 40><<<grid, 256, 0, stream>>>(bufB, ell, fill, norm_dst, b1, W2, norm_src, bufA);
    // Final: out = agg(XW2)*nd + b2  (fp32)
    k_agg_f<40><<<grid, 320, 0, stream>>>(bufA, ell, fill, norm_dst, b2, out);
}